// Round 14
// baseline (241.490 us; speedup 1.0000x reference)
//
#include <hip/hip_runtime.h>
#include <math.h>

#define DIMC 96
#define DINC 192
#define NSTC 16
#define DTRC 6
#define KDIR 4
#define BB   2
#define HH   56
#define WWD  56
#define LL   3136
#define NPIX (BB*LL)           // 6272
#define EPSF 1e-5f
#define NCH  196               // chunks per chain
#define LC   16                // chunk length (196*16=3136)
#define NCHAIN (BB*KDIR*DINC)  // 1536
#define NCOLS 152              // 4*38

// ---------- workspace layout (float offsets) ----------
#define OFF_XCRAW  0u          // 1204224 (gemm1->dwconv)
#define OFF_XCONV  1204224u    // 1204224 (dwconv->gemmx)
#define OFF_ZS     2408448u    // 1204224 (gemm1->gemm2)
#define OFF_DTS    3612672u    // 150528
#define OFF_BCB    3763200u    // 401408
#define OFF_BCC    4164608u    // 401408
#define OFF_XSCANT 4566016u    // 2408448 [b*2+slice][l][d] (2 slices; k>=2 read reversed)
#define OFF_CUMD   6974464u    // 4816896 (pass1->pass2)
#define OFF_YS     11791360u   // 4816896 (pass1->pass2 in-place ->gemm2)
#define OFF_HENDT  16608256u   // 4816896 = 8*196*16*192 (pass1->scan2->pass2)
#define OFF_SUMDT  21425152u   // 301056  = 8*196*192 -> ends 21726208
// post-pass2 (CUMD dead):
#define OFF_VL     6974464u    // 602112
#define OFF_H1     7576576u    // 150528
#define OFF_H2     7727104u    // 150528
#define OFF_H3     7877632u    // 602112
#define OFF_POOL   8479744u    // 192
#define OFF_SEW    8479936u    // 192

__device__ __forceinline__ float siluf(float x) { return x / (1.f + __expf(-x)); }
__device__ __forceinline__ float softplusf(float x) {
    return fmaxf(x, 0.f) + __logf(1.f + __expf(-fabsf(x)));
}
__device__ __forceinline__ float fexp2(float x) {
#if __has_builtin(__builtin_amdgcn_exp2f)
    return __builtin_amdgcn_exp2f(x);
#else
    return exp2f(x);
#endif
}
#define LOG2E 1.44269504088896f

// ---------- 1. fused LN1 + in_proj GEMM. grid (196,4) x 256. M=32,N=96 ----------
__global__ __launch_bounds__(256) void gemm1_k(const float* __restrict__ x,
                                               const float* __restrict__ g,
                                               const float* __restrict__ bt,
                                               const float* __restrict__ W,
                                               float* __restrict__ xcr,
                                               float* __restrict__ zs) {
    __shared__ float xT[32 * 97];
    __shared__ float wT[96 * 100];
    __shared__ float mA[32], iA[32];
    int row0 = blockIdx.x * 32;
    int b = row0 / LL, pos0 = row0 % LL;
    int by = blockIdx.y;
    int c0 = by * 96;
    for (int f = threadIdx.x; f < 96 * 8; f += 256) {
        int ch = f >> 3, po = (f & 7) * 4;
        float4 v = *(const float4*)&x[((size_t)b * DIMC + ch) * LL + pos0 + po];
        xT[(po + 0) * 97 + ch] = v.x; xT[(po + 1) * 97 + ch] = v.y;
        xT[(po + 2) * 97 + ch] = v.z; xT[(po + 3) * 97 + ch] = v.w;
    }
    for (int f = threadIdx.x; f < 96 * 24; f += 256) {
        int r = f / 24, kq = (f % 24) * 4;
        *(float4*)&wT[r * 100 + kq] = *(const float4*)&W[(size_t)(c0 + r) * DIMC + kq];
    }
    __syncthreads();
    {   // LN stats: 32 rows x 8 lanes
        int r = threadIdx.x >> 3, sc = threadIdx.x & 7;
        float s = 0.f, q = 0.f;
#pragma unroll
        for (int j = 0; j < 12; ++j) {
            float v = xT[r * 97 + sc + 8 * j];
            s += v; q = fmaf(v, v, q);
        }
        s += __shfl_xor(s, 1, 8); q += __shfl_xor(q, 1, 8);
        s += __shfl_xor(s, 2, 8); q += __shfl_xor(q, 2, 8);
        s += __shfl_xor(s, 4, 8); q += __shfl_xor(q, 4, 8);
        if (sc == 0) {
            float m = s * (1.f / 96.f);
            mA[r] = m;
            iA[r] = rsqrtf(q * (1.f / 96.f) - m * m + EPSF);
        }
    }
    __syncthreads();
    for (int e = threadIdx.x; e < 32 * 96; e += 256) {
        int row = e / 96, col = e - row * 96;
        float v = xT[row * 97 + col];
        xT[row * 97 + col] = (v - mA[row]) * iA[row] * g[col] + bt[col];
    }
    __syncthreads();
    int m = threadIdx.x & 31, cg = threadIdx.x >> 5;   // 8 col groups
    float acc[12] = {};
    for (int k = 0; k < 96; ++k) {
        float xv = xT[m * 97 + k];
#pragma unroll
        for (int j = 0; j < 12; ++j) acc[j] = fmaf(xv, wT[(cg + 8 * j) * 100 + k], acc[j]);
    }
    if (c0 < DINC) {
        // NCHW: lanes m consecutive pos -> coalesced per (cg,j)
#pragma unroll
        for (int j = 0; j < 12; ++j) {
            int col = c0 + cg + 8 * j;
            xcr[((size_t)b * DINC + col) * LL + pos0 + m] = acc[j];
        }
    } else {
        __syncthreads();
#pragma unroll
        for (int j = 0; j < 12; ++j) xT[m * 97 + cg + 8 * j] = acc[j];
        __syncthreads();
        int zoff = (by - 2) * 96;
        for (int e = threadIdx.x; e < 32 * 96; e += 256) {
            int r = e / 96, cq = e - 96 * (e / 96);
            zs[(size_t)(row0 + r) * DINC + zoff + cq] = siluf(xT[r * 97 + cq]);
        }
    }
}

// ---------- 2. depthwise 3x3 conv + silu -> xconv ----------
__global__ __launch_bounds__(448) void dwconv_k(const float* __restrict__ xcr,
                                                const float* __restrict__ cw,
                                                const float* __restrict__ cb,
                                                float* __restrict__ xconv) {
    __shared__ float P[56 * 57];
    int bd = blockIdx.x;
    int d = bd % DINC;
    size_t base = (size_t)bd * LL;
    for (int t = threadIdx.x; t < LL; t += 448)
        P[(t / 56) * 57 + (t % 56)] = xcr[base + t];
    float wk[9];
#pragma unroll
    for (int q = 0; q < 9; ++q) wk[q] = cw[d * 9 + q];
    float bias = cb[d];
    __syncthreads();
    for (int t = threadIdx.x; t < LL; t += 448) {
        int h = t / 56, w = t % 56;
        float acc = bias;
#pragma unroll
        for (int ky = 0; ky < 3; ++ky) {
            int y = h + ky - 1;
            if ((unsigned)y >= 56u) continue;
#pragma unroll
            for (int kx = 0; kx < 3; ++kx) {
                int xq = w + kx - 1;
                if ((unsigned)xq >= 56u) continue;
                acc = fmaf(wk[ky * 3 + kx], P[y * 57 + xq], acc);
            }
        }
        xconv[base + t] = siluf(acc);
    }
}

// ---------- 3. x_proj GEMM, band = direction. grid (196,4) x 256. M=32,N=38 ----------
__global__ __launch_bounds__(256) void gemmx_k(const float* __restrict__ xconv,
                                               const float* __restrict__ xpw,
                                               float* __restrict__ dts,
                                               float* __restrict__ bcB,
                                               float* __restrict__ bcC,
                                               float* __restrict__ xscanT) {
    __shared__ float xT[32 * 49];
    __shared__ float wT[38 * 52];
    int row0 = blockIdx.x * 32;
    int b = row0 / LL, pos0 = row0 % LL;
    int by = blockIdx.y;               // direction k
    int m = threadIdx.x & 31, cg = threadIdx.x >> 5;
    float acc[5] = {};
    for (int kc = 0; kc < 4; ++kc) {
        if (kc) __syncthreads();
        for (int f = threadIdx.x; f < 48 * 8; f += 256) {
            int dd = f >> 3, po = (f & 7) * 4;
            float4 v = *(const float4*)&xconv[((size_t)b * DINC + kc * 48 + dd) * LL + pos0 + po];
            xT[(po + 0) * 49 + dd] = v.x; xT[(po + 1) * 49 + dd] = v.y;
            xT[(po + 2) * 49 + dd] = v.z; xT[(po + 3) * 49 + dd] = v.w;
        }
        for (int f = threadIdx.x; f < 38 * 12; f += 256) {
            int r = f / 12, kq = (f % 12) * 4;
            *(float4*)&wT[r * 52 + kq] =
                *(const float4*)&xpw[(size_t)(by * 38 + r) * DINC + kc * 48 + kq];
        }
        __syncthreads();
#pragma unroll 4
        for (int k = 0; k < 48; ++k) {
            float xv = xT[m * 49 + k];
#pragma unroll
            for (int j = 0; j < 5; ++j) {
                int idx = cg + 8 * j;
                float wv = (idx < 38) ? wT[idx * 52 + k] : 0.f;
                acc[j] = fmaf(xv, wv, acc[j]);
            }
        }
        if (by == 0) {
            for (int f = threadIdx.x; f < 32 * 48; f += 256) {
                int i = f / 48, dd = f - 48 * (f / 48);
                float v = xT[i * 49 + dd];
                int pos = pos0 + i;
                int hh = pos / 56, w = pos - 56 * hh;
                int lt = w * 56 + hh;
                size_t bb = (size_t)b * 2;
                int col = kc * 48 + dd;
                xscanT[(bb * LL + pos) * DINC + col] = v;
                xscanT[((bb + 1) * LL + lt) * DINC + col] = v;
            }
        }
    }
    {
        int pos = pos0 + m;
        int h = pos / 56, w = pos - 56 * h;
        int lt = w * 56 + h;
        int l = (by == 0) ? pos : (by == 1) ? lt : (by == 2) ? (LL - 1 - pos) : (LL - 1 - lt);
        size_t rb = (size_t)(b * KDIR + by) * LL + l;
#pragma unroll
        for (int j = 0; j < 5; ++j) {
            int idx = cg + 8 * j;
            if (idx >= 38) continue;
            float v = acc[j];
            if (idx < DTRC)    dts[rb * DTRC + idx] = v;
            else if (idx < 22) bcB[rb * NSTC + (idx - 6)] = v;
            else               bcC[rb * NSTC + (idx - 22)] = v;
        }
    }
}

// ---------- 4a. pass1: d-per-thread local scan. grid 8*3*196 = 4704 x 64 ----------
__global__ __launch_bounds__(64) void pass1_k(const float* __restrict__ dts,
                                              const float* __restrict__ bcB,
                                              const float* __restrict__ bcC,
                                              const float* __restrict__ alog,
                                              const float* __restrict__ dtw,
                                              const float* __restrict__ dtb,
                                              const float* __restrict__ xscanT,
                                              float* __restrict__ hendT,
                                              float* __restrict__ sumdT,
                                              float* __restrict__ ysT,
                                              float* __restrict__ cumdT) {
    __shared__ float sdt[LC * 7];
    __shared__ float sB[LC * 16];
    __shared__ float sC[LC * 16];
    int blk = blockIdx.x;
    int c = blk % NCH;
    int dtile = (blk / NCH) % 3;
    int bk = blk / (NCH * 3);
    int k = bk & 3, b = bk >> 2;
    int l0 = c * LC;
    int t = threadIdx.x;
    int d = dtile * 64 + t;
    const float* dsrc = dts + ((size_t)bk * LL + l0) * DTRC;
    for (int f = t; f < LC * DTRC; f += 64) sdt[(f / DTRC) * 7 + (f % DTRC)] = dsrc[f];
    const float* bB = bcB + ((size_t)bk * LL + l0) * NSTC;
    const float* bC = bcC + ((size_t)bk * LL + l0) * NSTC;
    for (int f = t; f < LC * NSTC; f += 64) { sB[f] = bB[f]; sC[f] = bC[f]; }
    float wr[DTRC];
    {
        const float* wp = dtw + ((size_t)k * DINC + d) * DTRC;
#pragma unroll
        for (int r = 0; r < DTRC; ++r) wr[r] = wp[r];
    }
    float bias = dtb[k * DINC + d];
    float An2[NSTC];
    {
        const float* ap = alog + ((size_t)(k * DINC + d)) * NSTC;
#pragma unroll
        for (int n = 0; n < NSTC; ++n) An2[n] = -__expf(ap[n]) * LOG2E;
    }
    __syncthreads();
    float h[NSTC];
#pragma unroll
    for (int n = 0; n < NSTC; ++n) h[n] = 0.f;
    float cum = 0.f;
    bool rev = (k >= 2);
    const float* xbase = xscanT + ((size_t)(b * 2 + (k & 1)) * LL) * DINC + d;
    int xi0 = rev ? (LL - 1 - l0) : l0;
    float* yrow = ysT + ((size_t)bk * LL + l0) * DINC + d;
    float* crow = cumdT + ((size_t)bk * LL + l0) * DINC + d;
#pragma unroll 8
    for (int s = 0; s < LC; ++s) {
        float acc = bias;
#pragma unroll
        for (int r = 0; r < DTRC; ++r) acc = fmaf(wr[r], sdt[s * 7 + r], acc);
        float dv = softplusf(acc);
        float xv = xbase[(size_t)(rev ? (xi0 - s) : (xi0 + s)) * DINC];
        cum += dv;
        float dx = dv * xv;
        const float4* B4 = (const float4*)&sB[s * 16];
        const float4* C4 = (const float4*)&sC[s * 16];
        float y = 0.f;
#pragma unroll
        for (int nq = 0; nq < 4; ++nq) {
            float4 Bv = B4[nq], Cv = C4[nq];
            float e0 = fexp2(An2[nq * 4 + 0] * dv);
            h[nq * 4 + 0] = fmaf(e0, h[nq * 4 + 0], dx * Bv.x);
            y = fmaf(h[nq * 4 + 0], Cv.x, y);
            float e1 = fexp2(An2[nq * 4 + 1] * dv);
            h[nq * 4 + 1] = fmaf(e1, h[nq * 4 + 1], dx * Bv.y);
            y = fmaf(h[nq * 4 + 1], Cv.y, y);
            float e2 = fexp2(An2[nq * 4 + 2] * dv);
            h[nq * 4 + 2] = fmaf(e2, h[nq * 4 + 2], dx * Bv.z);
            y = fmaf(h[nq * 4 + 2], Cv.z, y);
            float e3 = fexp2(An2[nq * 4 + 3] * dv);
            h[nq * 4 + 3] = fmaf(e3, h[nq * 4 + 3], dx * Bv.w);
            y = fmaf(h[nq * 4 + 3], Cv.w, y);
        }
        yrow[(size_t)s * DINC] = y;
        crow[(size_t)s * DINC] = cum;
    }
#pragma unroll
    for (int n = 0; n < NSTC; ++n)
        hendT[((size_t)(bk * NCH + c) * NSTC + n) * DINC + d] = h[n];
    sumdT[(size_t)(bk * NCH + c) * DINC + d] = cum;
}

// ---------- 4b. scan2: thread=(d,n), serial over chunks. grid 96 x 256 ----------
__global__ __launch_bounds__(256) void scan2_k(float* __restrict__ hendT,
                                               const float* __restrict__ sumdT,
                                               const float* __restrict__ alog) {
    int gid = blockIdx.x * 256 + threadIdx.x;
    int d = gid % DINC;
    int n = (gid / DINC) % NSTC;
    int bk = gid / (DINC * NSTC);
    int k = bk & 3;
    float An2 = -__expf(alog[((size_t)(k * DINC + d)) * NSTC + n]) * LOG2E;
    float h = 0.f;
#pragma unroll 4
    for (int c = 0; c < NCH; ++c) {
        size_t idx = ((size_t)(bk * NCH + c) * NSTC + n) * DINC + d;
        float he = hendT[idx];
        float sd = sumdT[(size_t)(bk * NCH + c) * DINC + d];
        hendT[idx] = h;
        h = fmaf(fexp2(An2 * sd), h, he);
    }
}

// ---------- 4c. pass2: y += sum_n C*exp2(A2*cumd)*hpre. grid 1568 x 256 ----------
__global__ __launch_bounds__(256) void pass2_k(const float* __restrict__ bcC,
                                               const float* __restrict__ alog,
                                               const float* __restrict__ hpreT,
                                               const float* __restrict__ cumdT,
                                               float* __restrict__ ysT) {
    __shared__ float sA2[DINC * 17];
    __shared__ float sH[DINC * 17];
    __shared__ float sC[LC * NSTC];
    int blk = blockIdx.x;
    int c = blk % NCH;
    int bk = blk / NCH;
    int k = bk & 3;
    int l0 = c * LC;
    int tid = threadIdx.x;
    const float* ap = alog + (size_t)k * DINC * NSTC;
    for (int f = tid; f < DINC * NSTC; f += 256) {
        int dq = f / NSTC, n = f % NSTC;
        sA2[dq * 17 + n] = -__expf(ap[f]) * LOG2E;
    }
    for (int f = tid; f < DINC * NSTC; f += 256) {
        int n = f / DINC, dq = f % DINC;
        sH[dq * 17 + n] = hpreT[((size_t)(bk * NCH + c) * NSTC + n) * DINC + dq];
    }
    const float* bC = bcC + ((size_t)bk * LL + l0) * NSTC;
    for (int f = tid; f < LC * NSTC; f += 256) sC[f] = bC[f];
    __syncthreads();
    for (int e = tid; e < LC * DINC; e += 256) {
        int li = e / DINC, d = e - DINC * (e / DINC);
        size_t gq = ((size_t)bk * LL + l0 + li) * DINC + d;
        float cd = cumdT[gq];
        float y = ysT[gq];
        const float* A = &sA2[d * 17];
        const float* Hp = &sH[d * 17];
        const float* Cp = &sC[li * NSTC];
#pragma unroll
        for (int n = 0; n < NSTC; ++n)
            y = fmaf(Hp[n] * fexp2(A[n] * cd), Cp[n], y);
        ysT[gq] = y;
    }
}

// ---------- 5. fused combine + out_norm*silu(z) + out_proj + residual. M=16, grid 392 ----------
__global__ __launch_bounds__(256) void gemm2_k(const float* __restrict__ ysT,
                                               const float* __restrict__ xscanT,
                                               const float* __restrict__ dsv,
                                               const float* __restrict__ g,
                                               const float* __restrict__ bt,
                                               const float* __restrict__ zs,
                                               const float* __restrict__ opw,
                                               const float* __restrict__ x,
                                               const float* __restrict__ sc1,
                                               float* __restrict__ vl) {
    __shared__ float xT[16 * 193];
    __shared__ float wT[96 * 52];
    __shared__ float mA[16], iA[16];
    __shared__ float sD[DINC];
    int row0 = blockIdx.x * 16;
    int b = row0 / LL, pos0 = row0 % LL;
    if (threadIdx.x < DINC)
        sD[threadIdx.x] = dsv[threadIdx.x] + dsv[DINC + threadIdx.x] +
                          dsv[2 * DINC + threadIdx.x] + dsv[3 * DINC + threadIdx.x];
    __syncthreads();
    size_t base = (size_t)b * KDIR * LL;
    size_t xbase = (size_t)b * 2 * LL;
    for (int f = threadIdx.x; f < 16 * DINC; f += 256) {
        int r = f / DINC, d = f - DINC * (f / DINC);
        int pos = pos0 + r;
        int hh = pos / 56, w = pos - 56 * hh;
        int lt = w * 56 + hh;
        float y = ysT[(base + pos) * DINC + d]
                + ysT[(base + LL + lt) * DINC + d]
                + ysT[(base + 2 * LL + (LL - 1 - pos)) * DINC + d]
                + ysT[(base + 3 * LL + (LL - 1 - lt)) * DINC + d];
        float xv = xscanT[(xbase + pos) * DINC + d];
        xT[r * 193 + d] = fmaf(xv, sD[d], y);
    }
    __syncthreads();
    {
        int r = threadIdx.x >> 4, sc = threadIdx.x & 15;
        float s = 0.f, q = 0.f;
#pragma unroll
        for (int j = 0; j < 12; ++j) {
            float v = xT[r * 193 + sc + 16 * j];
            s += v; q = fmaf(v, v, q);
        }
        s += __shfl_xor(s, 1, 16); q += __shfl_xor(q, 1, 16);
        s += __shfl_xor(s, 2, 16); q += __shfl_xor(q, 2, 16);
        s += __shfl_xor(s, 4, 16); q += __shfl_xor(q, 4, 16);
        s += __shfl_xor(s, 8, 16); q += __shfl_xor(q, 8, 16);
        if (sc == 0) {
            float m = s * (1.f / 192.f);
            mA[r] = m;
            iA[r] = rsqrtf(q * (1.f / 192.f) - m * m + EPSF);
        }
    }
    __syncthreads();
    for (int e = threadIdx.x; e < 16 * 192; e += 256) {
        int row = e / 192, col = e - row * 192;
        float v = xT[row * 193 + col];
        float z = zs[(size_t)row0 * DINC + e];
        xT[row * 193 + col] = ((v - mA[row]) * iA[row] * g[col] + bt[col]) * z;
    }
    int tc = threadIdx.x & 15, tr = threadIdx.x >> 4;
    float acc[6] = {};
    for (int kc = 0; kc < 4; ++kc) {
        __syncthreads();
        for (int f = threadIdx.x; f < 96 * 12; f += 256) {
            int r = f / 12, kq = (f % 12) * 4;
            *(float4*)&wT[r * 52 + kq] = *(const float4*)&opw[(size_t)r * DINC + kc * 48 + kq];
        }
        __syncthreads();
#pragma unroll 4
        for (int k = 0; k < 48; ++k) {
            float xv = xT[tr * 193 + kc * 48 + k];
#pragma unroll
            for (int j = 0; j < 6; ++j) acc[j] = fmaf(xv, wT[(tc + 16 * j) * 52 + k], acc[j]);
        }
    }
    {
        int pos = pos0 + tr;
#pragma unroll
        for (int j = 0; j < 6; ++j) {
            int col = tc + 16 * j;
            float v = fmaf(sc1[col], x[((size_t)b * DIMC + col) * LL + pos], acc[j]);
            vl[(size_t)(row0 + tr) * DIMC + col] = v;
        }
    }
}

// ---------- 6. LN2 + conv1x1(96->24) + BN + ReLU ----------
__global__ __launch_bounds__(256) void ln2conv1_k(const float* __restrict__ vl,
                                                  const float* __restrict__ g,
                                                  const float* __restrict__ bt,
                                                  const float* __restrict__ w1,
                                                  const float* __restrict__ g1,
                                                  const float* __restrict__ b1,
                                                  const float* __restrict__ m1,
                                                  const float* __restrict__ v1,
                                                  float* __restrict__ h1) {
    __shared__ float row[4][96];
    int wv = threadIdx.x >> 6, lane = threadIdx.x & 63;
    int pix = blockIdx.x * 4 + wv;
    const float* vr = vl + (size_t)pix * DIMC;
    float a0 = vr[lane];
    float a1 = (lane < 32) ? vr[64 + lane] : 0.f;
    float s = a0 + a1, q = a0 * a0 + a1 * a1;
    for (int o = 32; o; o >>= 1) { s += __shfl_xor(s, o, 64); q += __shfl_xor(q, o, 64); }
    float m = s * (1.f / 96.f);
    float inv = rsqrtf(q * (1.f / 96.f) - m * m + EPSF);
    row[wv][lane] = (a0 - m) * inv * g[lane] + bt[lane];
    if (lane < 32) row[wv][64 + lane] = (a1 - m) * inv * g[64 + lane] + bt[64 + lane];
    __syncthreads();
    if (lane < 24) {
        const float* wr = w1 + lane * 96;
        float acc = 0.f;
#pragma unroll 8
        for (int c = 0; c < 96; ++c) acc = fmaf(row[wv][c], wr[c], acc);
        float bn = (acc - m1[lane]) * rsqrtf(v1[lane] + EPSF) * g1[lane] + b1[lane];
        int b = pix / LL, pos = pix % LL;
        h1[((size_t)b * 24 + lane) * LL + pos] = fmaxf(bn, 0.f);
    }
}

// ---------- 7. conv3x3 (24->24) + BN + ReLU ----------
__global__ __launch_bounds__(256) void conv2_k(const float* __restrict__ h1,
                                               const float* __restrict__ w2,
                                               const float* __restrict__ g2,
                                               const float* __restrict__ b2,
                                               const float* __restrict__ m2,
                                               const float* __restrict__ v2,
                                               float* __restrict__ h2) {
    int i = blockIdx.x * 256 + threadIdx.x;
    int pos = i % LL, mo = (i / LL) % 24, b = i / (LL * 24);
    int hh = pos / WWD, ww = pos % WWD;
    float acc = 0.f;
    for (int c = 0; c < 24; ++c) {
        const float* src = h1 + ((size_t)b * 24 + c) * LL;
        const float* wk = w2 + ((size_t)(mo * 24 + c)) * 9;
#pragma unroll
        for (int ky = 0; ky < 3; ++ky) {
            int y = hh + ky - 1;
            if ((unsigned)y >= HH) continue;
#pragma unroll
            for (int kx = 0; kx < 3; ++kx) {
                int xq = ww + kx - 1;
                if ((unsigned)xq >= WWD) continue;
                acc = fmaf(wk[ky * 3 + kx], src[y * WWD + xq], acc);
            }
        }
    }
    float bn = (acc - m2[mo]) * rsqrtf(v2[mo] + EPSF) * g2[mo] + b2[mo];
    h2[i] = fmaxf(bn, 0.f);
}

// ---------- 8. conv1x1 (24->96) + BN ----------
__global__ __launch_bounds__(256) void conv3_k(const float* __restrict__ h2,
                                               const float* __restrict__ w3,
                                               const float* __restrict__ g3,
                                               const float* __restrict__ b3,
                                               const float* __restrict__ m3,
                                               const float* __restrict__ v3,
                                               float* __restrict__ h3) {
    int i = blockIdx.x * 256 + threadIdx.x;
    int pos = i % LL, c = (i / LL) % DIMC, b = i / (LL * DIMC);
    const float* wr = w3 + c * 24;
    float acc = 0.f;
#pragma unroll
    for (int mo = 0; mo < 24; ++mo)
        acc = fmaf(wr[mo], h2[((size_t)b * 24 + mo) * LL + pos], acc);
    h3[i] = (acc - m3[c]) * rsqrtf(v3[c] + EPSF) * g3[c] + b3[c];
}

// ---------- 9. SE pool ----------
__global__ __launch_bounds__(256) void pool_k(const float* __restrict__ h3,
                                              float* __restrict__ pooled) {
    int bc = blockIdx.x;
    const float* p = h3 + (size_t)bc * LL;
    float s = 0.f;
    for (int i = threadIdx.x; i < LL; i += 256) s += p[i];
    for (int o = 32; o; o >>= 1) s += __shfl_xor(s, o, 64);
    __shared__ float wsum[4];
    if ((threadIdx.x & 63) == 0) wsum[threadIdx.x >> 6] = s;
    __syncthreads();
    if (threadIdx.x == 0) pooled[bc] = (wsum[0] + wsum[1] + wsum[2] + wsum[3]) * (1.f / 3136.f);
}

// ---------- 10. SE MLP ----------
__global__ __launch_bounds__(128) void semlp_k(const float* __restrict__ pooled,
                                               const float* __restrict__ sw1,
                                               const float* __restrict__ sw2,
                                               float* __restrict__ sew) {
    __shared__ float pl[2][96];
    __shared__ float hid[2][24];
    for (int i = threadIdx.x; i < 192; i += 128) pl[i / 96][i % 96] = pooled[i];
    __syncthreads();
    if (threadIdx.x < 48) {
        int b = threadIdx.x / 24, mo = threadIdx.x % 24;
        float acc = 0.f;
        for (int c = 0; c < 96; ++c) acc = fmaf(pl[b][c], sw1[mo * 96 + c], acc);
        hid[b][mo] = fmaxf(acc, 0.f);
    }
    __syncthreads();
    for (int i = threadIdx.x; i < 192; i += 128) {
        int b = i / 96, c = i % 96;
        float acc = 0.f;
        for (int mo = 0; mo < 24; ++mo) acc = fmaf(hid[b][mo], sw2[c * 24 + mo], acc);
        sew[i] = 1.f / (1.f + __expf(-acc));
    }
}

// ---------- 11. final ----------
__global__ __launch_bounds__(256) void final_k(const float* __restrict__ h3,
                                               const float* __restrict__ sew,
                                               const float* __restrict__ vl,
                                               const float* __restrict__ sc2,
                                               float* __restrict__ out) {
    int i = blockIdx.x * 256 + threadIdx.x;
    int pos = i % LL, c = (i / LL) % DIMC, b = i / (LL * DIMC);
    out[i] = fmaf(h3[i], sew[b * DIMC + c],
                  sc2[c] * vl[((size_t)b * LL + pos) * DIMC + c]);
}

extern "C" void kernel_launch(void* const* d_in, const int* in_sizes, int n_in,
                              void* d_out, int out_size, void* d_ws, size_t ws_size,
                              hipStream_t stream) {
    const float* x    = (const float*)d_in[0];
    const float* n1g  = (const float*)d_in[1];
    const float* n1b  = (const float*)d_in[2];
    const float* ipw  = (const float*)d_in[3];
    const float* cw   = (const float*)d_in[4];
    const float* cb   = (const float*)d_in[5];
    const float* xpw  = (const float*)d_in[6];
    const float* dtw  = (const float*)d_in[7];
    const float* dtb  = (const float*)d_in[8];
    const float* alog = (const float*)d_in[9];
    const float* dsv  = (const float*)d_in[10];
    const float* ong  = (const float*)d_in[11];
    const float* onb  = (const float*)d_in[12];
    const float* opw  = (const float*)d_in[13];
    const float* sc1  = (const float*)d_in[14];
    const float* n2g  = (const float*)d_in[15];
    const float* n2b  = (const float*)d_in[16];
    const float* w1   = (const float*)d_in[17];
    const float* g1   = (const float*)d_in[18];
    const float* b1   = (const float*)d_in[19];
    const float* m1   = (const float*)d_in[20];
    const float* v1   = (const float*)d_in[21];
    const float* w2   = (const float*)d_in[22];
    const float* g2   = (const float*)d_in[23];
    const float* b2   = (const float*)d_in[24];
    const float* m2   = (const float*)d_in[25];
    const float* v2   = (const float*)d_in[26];
    const float* w3   = (const float*)d_in[27];
    const float* g3   = (const float*)d_in[28];
    const float* b3   = (const float*)d_in[29];
    const float* m3   = (const float*)d_in[30];
    const float* v3   = (const float*)d_in[31];
    const float* sw1  = (const float*)d_in[32];
    const float* sw2  = (const float*)d_in[33];
    const float* sc2  = (const float*)d_in[34];
    float* ws = (float*)d_ws;
    float* out = (float*)d_out;

    gemm1_k<<<dim3(NPIX / 32, 4), 256, 0, stream>>>(x, n1g, n1b, ipw,
                                                    ws + OFF_XCRAW, ws + OFF_ZS);
    dwconv_k<<<BB * DINC, 448, 0, stream>>>(ws + OFF_XCRAW, cw, cb, ws + OFF_XCONV);
    gemmx_k<<<dim3(NPIX / 32, 4), 256, 0, stream>>>(ws + OFF_XCONV, xpw, ws + OFF_DTS,
                                                    ws + OFF_BCB, ws + OFF_BCC, ws + OFF_XSCANT);

    pass1_k<<<BB * KDIR * 3 * NCH, 64, 0, stream>>>(
        ws + OFF_DTS, ws + OFF_BCB, ws + OFF_BCC, alog, dtw, dtb,
        ws + OFF_XSCANT, ws + OFF_HENDT, ws + OFF_SUMDT, ws + OFF_YS, ws + OFF_CUMD);
    scan2_k<<<(NCHAIN * NSTC) / 256, 256, 0, stream>>>(ws + OFF_HENDT, ws + OFF_SUMDT, alog);
    pass2_k<<<BB * KDIR * NCH, 256, 0, stream>>>(
        ws + OFF_BCC, alog, ws + OFF_HENDT, ws + OFF_CUMD, ws + OFF_YS);

    gemm2_k<<<NPIX / 16, 256, 0, stream>>>(ws + OFF_YS, ws + OFF_XSCANT, dsv,
                                           ong, onb, ws + OFF_ZS, opw, x, sc1, ws + OFF_VL);
    ln2conv1_k<<<NPIX / 4, 256, 0, stream>>>(ws + OFF_VL, n2g, n2b, w1, g1, b1, m1, v1,
                                             ws + OFF_H1);
    conv2_k<<<(BB * 24 * LL) / 256, 256, 0, stream>>>(ws + OFF_H1, w2, g2, b2, m2, v2,
                                                      ws + OFF_H2);
    conv3_k<<<(BB * DIMC * LL) / 256, 256, 0, stream>>>(ws + OFF_H2, w3, g3, b3, m3, v3,
                                                        ws + OFF_H3);
    pool_k<<<BB * DIMC, 256, 0, stream>>>(ws + OFF_H3, ws + OFF_POOL);
    semlp_k<<<1, 128, 0, stream>>>(ws + OFF_POOL, sw1, sw2, ws + OFF_SEW);
    final_k<<<(BB * DIMC * LL) / 256, 256, 0, stream>>>(ws + OFF_H3, ws + OFF_SEW, ws + OFF_VL,
                                                        sc2, out);
    (void)in_sizes; (void)n_in; (void)out_size; (void)ws_size;
}

// Round 15
// 229.766 us; speedup vs baseline: 1.0510x; 1.0510x over previous
//
#include <hip/hip_runtime.h>
#include <math.h>

#define DIMC 96
#define DINC 192
#define NSTC 16
#define DTRC 6
#define KDIR 4
#define BB   2
#define HH   56
#define WWD  56
#define LL   3136
#define NPIX (BB*LL)           // 6272
#define EPSF 1e-5f
#define NCH  98                // chunks per chain
#define LC   32                // chunk length (98*32=3136)
#define NCHAIN (BB*KDIR*DINC)  // 1536
#define NCOLS 152              // 4*38

// ---------- workspace layout (float offsets) ----------
#define OFF_XCRAW  0u          // 1204224 (gemm1->dwconv)
#define OFF_XCONV  1204224u    // 1204224 (dwconv->gemmx)
#define OFF_ZS     2408448u    // 1204224 (gemm1->gemm2)
#define OFF_DTS    3612672u    // 150528
#define OFF_BCB    3763200u    // 401408
#define OFF_BCC    4164608u    // 401408
#define OFF_XSCANT 4566016u    // 2408448 [b*2+slice][l][d] (2 slices; k>=2 read reversed)
#define OFF_CUMD   6974464u    // 4816896 (pass1->pass2)
#define OFF_YS     11791360u   // 4816896 (pass1->pass2 in-place ->gemm2)
#define OFF_HENDT  0u          // 2408448 = 8*98*16*192, reuses XCRAW+XCONV (dead after gemmx)
#define OFF_SUMDT  16608256u   // 150528 -> ends 16758784
// post-pass2 (CUMD dead):
#define OFF_VL     6974464u    // 602112
#define OFF_H1     7576576u    // 150528
#define OFF_H2     7727104u    // 150528
#define OFF_H3     7877632u    // 602112
#define OFF_POOL   8479744u    // 192
#define OFF_SEW    8479936u    // 192

__device__ __forceinline__ float siluf(float x) { return x / (1.f + __expf(-x)); }
__device__ __forceinline__ float softplusf(float x) {
    return fmaxf(x, 0.f) + __logf(1.f + __expf(-fabsf(x)));
}
__device__ __forceinline__ float fexp2(float x) {
#if __has_builtin(__builtin_amdgcn_exp2f)
    return __builtin_amdgcn_exp2f(x);
#else
    return exp2f(x);
#endif
}
#define LOG2E 1.44269504088896f

// ---------- 1. fused LN1 + in_proj GEMM. grid (196,4) x 256. M=32,N=96 ----------
__global__ __launch_bounds__(256) void gemm1_k(const float* __restrict__ x,
                                               const float* __restrict__ g,
                                               const float* __restrict__ bt,
                                               const float* __restrict__ W,
                                               float* __restrict__ xcr,
                                               float* __restrict__ zs) {
    __shared__ float xT[32 * 97];
    __shared__ float wT[96 * 100];
    __shared__ float mA[32], iA[32];
    int row0 = blockIdx.x * 32;
    int b = row0 / LL, pos0 = row0 % LL;
    int by = blockIdx.y;
    int c0 = by * 96;
    for (int f = threadIdx.x; f < 96 * 8; f += 256) {
        int ch = f >> 3, po = (f & 7) * 4;
        float4 v = *(const float4*)&x[((size_t)b * DIMC + ch) * LL + pos0 + po];
        xT[(po + 0) * 97 + ch] = v.x; xT[(po + 1) * 97 + ch] = v.y;
        xT[(po + 2) * 97 + ch] = v.z; xT[(po + 3) * 97 + ch] = v.w;
    }
    for (int f = threadIdx.x; f < 96 * 24; f += 256) {
        int r = f / 24, kq = (f % 24) * 4;
        *(float4*)&wT[r * 100 + kq] = *(const float4*)&W[(size_t)(c0 + r) * DIMC + kq];
    }
    __syncthreads();
    {   // LN stats: 32 rows x 8 lanes
        int r = threadIdx.x >> 3, sc = threadIdx.x & 7;
        float s = 0.f, q = 0.f;
#pragma unroll
        for (int j = 0; j < 12; ++j) {
            float v = xT[r * 97 + sc + 8 * j];
            s += v; q = fmaf(v, v, q);
        }
        s += __shfl_xor(s, 1, 8); q += __shfl_xor(q, 1, 8);
        s += __shfl_xor(s, 2, 8); q += __shfl_xor(q, 2, 8);
        s += __shfl_xor(s, 4, 8); q += __shfl_xor(q, 4, 8);
        if (sc == 0) {
            float m = s * (1.f / 96.f);
            mA[r] = m;
            iA[r] = rsqrtf(q * (1.f / 96.f) - m * m + EPSF);
        }
    }
    __syncthreads();
    for (int e = threadIdx.x; e < 32 * 96; e += 256) {
        int row = e / 96, col = e - row * 96;
        float v = xT[row * 97 + col];
        xT[row * 97 + col] = (v - mA[row]) * iA[row] * g[col] + bt[col];
    }
    __syncthreads();
    int m = threadIdx.x & 31, cg = threadIdx.x >> 5;   // 8 col groups
    float acc[12] = {};
    for (int k = 0; k < 96; ++k) {
        float xv = xT[m * 97 + k];
#pragma unroll
        for (int j = 0; j < 12; ++j) acc[j] = fmaf(xv, wT[(cg + 8 * j) * 100 + k], acc[j]);
    }
    if (c0 < DINC) {
#pragma unroll
        for (int j = 0; j < 12; ++j) {
            int col = c0 + cg + 8 * j;
            xcr[((size_t)b * DINC + col) * LL + pos0 + m] = acc[j];
        }
    } else {
        __syncthreads();
#pragma unroll
        for (int j = 0; j < 12; ++j) xT[m * 97 + cg + 8 * j] = acc[j];
        __syncthreads();
        int zoff = (by - 2) * 96;
        for (int e = threadIdx.x; e < 32 * 96; e += 256) {
            int r = e / 96, cq = e - 96 * (e / 96);
            zs[(size_t)(row0 + r) * DINC + zoff + cq] = siluf(xT[r * 97 + cq]);
        }
    }
}

// ---------- 2. depthwise 3x3 conv + silu -> xconv ----------
__global__ __launch_bounds__(448) void dwconv_k(const float* __restrict__ xcr,
                                                const float* __restrict__ cw,
                                                const float* __restrict__ cb,
                                                float* __restrict__ xconv) {
    __shared__ float P[56 * 57];
    int bd = blockIdx.x;
    int d = bd % DINC;
    size_t base = (size_t)bd * LL;
    for (int t = threadIdx.x; t < LL; t += 448)
        P[(t / 56) * 57 + (t % 56)] = xcr[base + t];
    float wk[9];
#pragma unroll
    for (int q = 0; q < 9; ++q) wk[q] = cw[d * 9 + q];
    float bias = cb[d];
    __syncthreads();
    for (int t = threadIdx.x; t < LL; t += 448) {
        int h = t / 56, w = t % 56;
        float acc = bias;
#pragma unroll
        for (int ky = 0; ky < 3; ++ky) {
            int y = h + ky - 1;
            if ((unsigned)y >= 56u) continue;
#pragma unroll
            for (int kx = 0; kx < 3; ++kx) {
                int xq = w + kx - 1;
                if ((unsigned)xq >= 56u) continue;
                acc = fmaf(wk[ky * 3 + kx], P[y * 57 + xq], acc);
            }
        }
        xconv[base + t] = siluf(acc);
    }
}

// ---------- 3. x_proj GEMM, band = direction. grid (196,4) x 256. M=32,N=38 ----------
__global__ __launch_bounds__(256) void gemmx_k(const float* __restrict__ xconv,
                                               const float* __restrict__ xpw,
                                               float* __restrict__ dts,
                                               float* __restrict__ bcB,
                                               float* __restrict__ bcC,
                                               float* __restrict__ xscanT) {
    __shared__ float xT[32 * 49];
    __shared__ float wT[38 * 52];
    int row0 = blockIdx.x * 32;
    int b = row0 / LL, pos0 = row0 % LL;
    int by = blockIdx.y;               // direction k
    int m = threadIdx.x & 31, cg = threadIdx.x >> 5;
    float acc[5] = {};
    for (int kc = 0; kc < 4; ++kc) {
        if (kc) __syncthreads();
        for (int f = threadIdx.x; f < 48 * 8; f += 256) {
            int dd = f >> 3, po = (f & 7) * 4;
            float4 v = *(const float4*)&xconv[((size_t)b * DINC + kc * 48 + dd) * LL + pos0 + po];
            xT[(po + 0) * 49 + dd] = v.x; xT[(po + 1) * 49 + dd] = v.y;
            xT[(po + 2) * 49 + dd] = v.z; xT[(po + 3) * 49 + dd] = v.w;
        }
        for (int f = threadIdx.x; f < 38 * 12; f += 256) {
            int r = f / 12, kq = (f % 12) * 4;
            *(float4*)&wT[r * 52 + kq] =
                *(const float4*)&xpw[(size_t)(by * 38 + r) * DINC + kc * 48 + kq];
        }
        __syncthreads();
#pragma unroll 4
        for (int k = 0; k < 48; ++k) {
            float xv = xT[m * 49 + k];
#pragma unroll
            for (int j = 0; j < 5; ++j) {
                int idx = cg + 8 * j;
                float wv = (idx < 38) ? wT[idx * 52 + k] : 0.f;
                acc[j] = fmaf(xv, wv, acc[j]);
            }
        }
        if (by == 0) {
            for (int f = threadIdx.x; f < 32 * 48; f += 256) {
                int i = f / 48, dd = f - 48 * (f / 48);
                float v = xT[i * 49 + dd];
                int pos = pos0 + i;
                int hh = pos / 56, w = pos - 56 * hh;
                int lt = w * 56 + hh;
                size_t bb = (size_t)b * 2;
                int col = kc * 48 + dd;
                xscanT[(bb * LL + pos) * DINC + col] = v;
                xscanT[((bb + 1) * LL + lt) * DINC + col] = v;
            }
        }
    }
    {
        int pos = pos0 + m;
        int h = pos / 56, w = pos - 56 * h;
        int lt = w * 56 + h;
        int l = (by == 0) ? pos : (by == 1) ? lt : (by == 2) ? (LL - 1 - pos) : (LL - 1 - lt);
        size_t rb = (size_t)(b * KDIR + by) * LL + l;
#pragma unroll
        for (int j = 0; j < 5; ++j) {
            int idx = cg + 8 * j;
            if (idx >= 38) continue;
            float v = acc[j];
            if (idx < DTRC)    dts[rb * DTRC + idx] = v;
            else if (idx < 22) bcB[rb * NSTC + (idx - 6)] = v;
            else               bcC[rb * NSTC + (idx - 22)] = v;
        }
    }
}

// ---------- 4a. pass1: d-per-thread local scan. grid 8*3*98 = 2352 x 64 ----------
__global__ __launch_bounds__(64) void pass1_k(const float* __restrict__ dts,
                                              const float* __restrict__ bcB,
                                              const float* __restrict__ bcC,
                                              const float* __restrict__ alog,
                                              const float* __restrict__ dtw,
                                              const float* __restrict__ dtb,
                                              const float* __restrict__ xscanT,
                                              float* __restrict__ hendT,
                                              float* __restrict__ sumdT,
                                              float* __restrict__ ysT,
                                              float* __restrict__ cumdT) {
    __shared__ float sdt[LC * 7];
    __shared__ float sB[LC * 16];
    __shared__ float sC[LC * 16];
    int blk = blockIdx.x;
    int c = blk % NCH;
    int dtile = (blk / NCH) % 3;
    int bk = blk / (NCH * 3);
    int k = bk & 3, b = bk >> 2;
    int l0 = c * LC;
    int t = threadIdx.x;
    int d = dtile * 64 + t;
    const float* dsrc = dts + ((size_t)bk * LL + l0) * DTRC;
    for (int f = t; f < LC * DTRC; f += 64) sdt[(f / DTRC) * 7 + (f % DTRC)] = dsrc[f];
    const float* bB = bcB + ((size_t)bk * LL + l0) * NSTC;
    const float* bC = bcC + ((size_t)bk * LL + l0) * NSTC;
    for (int f = t; f < LC * NSTC; f += 64) { sB[f] = bB[f]; sC[f] = bC[f]; }
    float wr[DTRC];
    {
        const float* wp = dtw + ((size_t)k * DINC + d) * DTRC;
#pragma unroll
        for (int r = 0; r < DTRC; ++r) wr[r] = wp[r];
    }
    float bias = dtb[k * DINC + d];
    float An2[NSTC];
    {
        const float* ap = alog + ((size_t)(k * DINC + d)) * NSTC;
#pragma unroll
        for (int n = 0; n < NSTC; ++n) An2[n] = -__expf(ap[n]) * LOG2E;
    }
    __syncthreads();
    float h[NSTC];
#pragma unroll
    for (int n = 0; n < NSTC; ++n) h[n] = 0.f;
    float cum = 0.f;
    bool rev = (k >= 2);
    const float* xbase = xscanT + ((size_t)(b * 2 + (k & 1)) * LL) * DINC + d;
    int xi0 = rev ? (LL - 1 - l0) : l0;
    float* yrow = ysT + ((size_t)bk * LL + l0) * DINC + d;
    float* crow = cumdT + ((size_t)bk * LL + l0) * DINC + d;
#pragma unroll 8
    for (int s = 0; s < LC; ++s) {
        float acc = bias;
#pragma unroll
        for (int r = 0; r < DTRC; ++r) acc = fmaf(wr[r], sdt[s * 7 + r], acc);
        float dv = softplusf(acc);
        float xv = xbase[(size_t)(rev ? (xi0 - s) : (xi0 + s)) * DINC];
        cum += dv;
        float dx = dv * xv;
        const float4* B4 = (const float4*)&sB[s * 16];
        const float4* C4 = (const float4*)&sC[s * 16];
        float y = 0.f;
#pragma unroll
        for (int nq = 0; nq < 4; ++nq) {
            float4 Bv = B4[nq], Cv = C4[nq];
            float e0 = fexp2(An2[nq * 4 + 0] * dv);
            h[nq * 4 + 0] = fmaf(e0, h[nq * 4 + 0], dx * Bv.x);
            y = fmaf(h[nq * 4 + 0], Cv.x, y);
            float e1 = fexp2(An2[nq * 4 + 1] * dv);
            h[nq * 4 + 1] = fmaf(e1, h[nq * 4 + 1], dx * Bv.y);
            y = fmaf(h[nq * 4 + 1], Cv.y, y);
            float e2 = fexp2(An2[nq * 4 + 2] * dv);
            h[nq * 4 + 2] = fmaf(e2, h[nq * 4 + 2], dx * Bv.z);
            y = fmaf(h[nq * 4 + 2], Cv.z, y);
            float e3 = fexp2(An2[nq * 4 + 3] * dv);
            h[nq * 4 + 3] = fmaf(e3, h[nq * 4 + 3], dx * Bv.w);
            y = fmaf(h[nq * 4 + 3], Cv.w, y);
        }
        yrow[(size_t)s * DINC] = y;
        crow[(size_t)s * DINC] = cum;
    }
#pragma unroll
    for (int n = 0; n < NSTC; ++n)
        hendT[((size_t)(bk * NCH + c) * NSTC + n) * DINC + d] = h[n];
    sumdT[(size_t)(bk * NCH + c) * DINC + d] = cum;
}

// ---------- 4b. scan2: thread=(d,n), serial over chunks. grid 96 x 256 ----------
__global__ __launch_bounds__(256) void scan2_k(float* __restrict__ hendT,
                                               const float* __restrict__ sumdT,
                                               const float* __restrict__ alog) {
    int gid = blockIdx.x * 256 + threadIdx.x;
    int d = gid % DINC;
    int n = (gid / DINC) % NSTC;
    int bk = gid / (DINC * NSTC);
    int k = bk & 3;
    float An2 = -__expf(alog[((size_t)(k * DINC + d)) * NSTC + n]) * LOG2E;
    float h = 0.f;
#pragma unroll 4
    for (int c = 0; c < NCH; ++c) {
        size_t idx = ((size_t)(bk * NCH + c) * NSTC + n) * DINC + d;
        float he = hendT[idx];
        float sd = sumdT[(size_t)(bk * NCH + c) * DINC + d];
        hendT[idx] = h;
        h = fmaf(fexp2(An2 * sd), h, he);
    }
}

// ---------- 4c. pass2: y += sum_n C*exp2(A2*cumd)*hpre. grid 784 x 256 ----------
__global__ __launch_bounds__(256) void pass2_k(const float* __restrict__ bcC,
                                               const float* __restrict__ alog,
                                               const float* __restrict__ hpreT,
                                               const float* __restrict__ cumdT,
                                               float* __restrict__ ysT) {
    __shared__ float sA2[DINC * 17];
    __shared__ float sH[DINC * 17];
    __shared__ float sC[LC * NSTC];
    int blk = blockIdx.x;
    int c = blk % NCH;
    int bk = blk / NCH;
    int k = bk & 3;
    int l0 = c * LC;
    int tid = threadIdx.x;
    const float* ap = alog + (size_t)k * DINC * NSTC;
    for (int f = tid; f < DINC * NSTC; f += 256) {
        int dq = f / NSTC, n = f % NSTC;
        sA2[dq * 17 + n] = -__expf(ap[f]) * LOG2E;
    }
    for (int f = tid; f < DINC * NSTC; f += 256) {
        int n = f / DINC, dq = f % DINC;
        sH[dq * 17 + n] = hpreT[((size_t)(bk * NCH + c) * NSTC + n) * DINC + dq];
    }
    const float* bC = bcC + ((size_t)bk * LL + l0) * NSTC;
    for (int f = tid; f < LC * NSTC; f += 256) sC[f] = bC[f];
    __syncthreads();
    for (int e = tid; e < LC * DINC; e += 256) {
        int li = e / DINC, d = e - DINC * (e / DINC);
        size_t gq = ((size_t)bk * LL + l0 + li) * DINC + d;
        float cd = cumdT[gq];
        float y = ysT[gq];
        const float* A = &sA2[d * 17];
        const float* Hp = &sH[d * 17];
        const float* Cp = &sC[li * NSTC];
#pragma unroll
        for (int n = 0; n < NSTC; ++n)
            y = fmaf(Hp[n] * fexp2(A[n] * cd), Cp[n], y);
        ysT[gq] = y;
    }
}

// ---------- 5. fused combine + out_norm*silu(z) + out_proj + residual. M=16, grid 392 ----------
__global__ __launch_bounds__(256) void gemm2_k(const float* __restrict__ ysT,
                                               const float* __restrict__ xscanT,
                                               const float* __restrict__ dsv,
                                               const float* __restrict__ g,
                                               const float* __restrict__ bt,
                                               const float* __restrict__ zs,
                                               const float* __restrict__ opw,
                                               const float* __restrict__ x,
                                               const float* __restrict__ sc1,
                                               float* __restrict__ vl) {
    __shared__ float xT[16 * 193];
    __shared__ float wT[96 * 52];
    __shared__ float mA[16], iA[16];
    __shared__ float sD[DINC];
    int row0 = blockIdx.x * 16;
    int b = row0 / LL, pos0 = row0 % LL;
    if (threadIdx.x < DINC)
        sD[threadIdx.x] = dsv[threadIdx.x] + dsv[DINC + threadIdx.x] +
                          dsv[2 * DINC + threadIdx.x] + dsv[3 * DINC + threadIdx.x];
    __syncthreads();
    size_t base = (size_t)b * KDIR * LL;
    size_t xbase = (size_t)b * 2 * LL;
    for (int f = threadIdx.x; f < 16 * DINC; f += 256) {
        int r = f / DINC, d = f - DINC * (f / DINC);
        int pos = pos0 + r;
        int hh = pos / 56, w = pos - 56 * hh;
        int lt = w * 56 + hh;
        float y = ysT[(base + pos) * DINC + d]
                + ysT[(base + LL + lt) * DINC + d]
                + ysT[(base + 2 * LL + (LL - 1 - pos)) * DINC + d]
                + ysT[(base + 3 * LL + (LL - 1 - lt)) * DINC + d];
        float xv = xscanT[(xbase + pos) * DINC + d];
        xT[r * 193 + d] = fmaf(xv, sD[d], y);
    }
    __syncthreads();
    {
        int r = threadIdx.x >> 4, sc = threadIdx.x & 15;
        float s = 0.f, q = 0.f;
#pragma unroll
        for (int j = 0; j < 12; ++j) {
            float v = xT[r * 193 + sc + 16 * j];
            s += v; q = fmaf(v, v, q);
        }
        s += __shfl_xor(s, 1, 16); q += __shfl_xor(q, 1, 16);
        s += __shfl_xor(s, 2, 16); q += __shfl_xor(q, 2, 16);
        s += __shfl_xor(s, 4, 16); q += __shfl_xor(q, 4, 16);
        s += __shfl_xor(s, 8, 16); q += __shfl_xor(q, 8, 16);
        if (sc == 0) {
            float m = s * (1.f / 192.f);
            mA[r] = m;
            iA[r] = rsqrtf(q * (1.f / 192.f) - m * m + EPSF);
        }
    }
    __syncthreads();
    for (int e = threadIdx.x; e < 16 * 192; e += 256) {
        int row = e / 192, col = e - row * 192;
        float v = xT[row * 193 + col];
        float z = zs[(size_t)row0 * DINC + e];
        xT[row * 193 + col] = ((v - mA[row]) * iA[row] * g[col] + bt[col]) * z;
    }
    int tc = threadIdx.x & 15, tr = threadIdx.x >> 4;
    float acc[6] = {};
    for (int kc = 0; kc < 4; ++kc) {
        __syncthreads();
        for (int f = threadIdx.x; f < 96 * 12; f += 256) {
            int r = f / 12, kq = (f % 12) * 4;
            *(float4*)&wT[r * 52 + kq] = *(const float4*)&opw[(size_t)r * DINC + kc * 48 + kq];
        }
        __syncthreads();
#pragma unroll 4
        for (int k = 0; k < 48; ++k) {
            float xv = xT[tr * 193 + kc * 48 + k];
#pragma unroll
            for (int j = 0; j < 6; ++j) acc[j] = fmaf(xv, wT[(tc + 16 * j) * 52 + k], acc[j]);
        }
    }
    {
        int pos = pos0 + tr;
#pragma unroll
        for (int j = 0; j < 6; ++j) {
            int col = tc + 16 * j;
            float v = fmaf(sc1[col], x[((size_t)b * DIMC + col) * LL + pos], acc[j]);
            vl[(size_t)(row0 + tr) * DIMC + col] = v;
        }
    }
}

// ---------- 6. LN2 + conv1x1(96->24) + BN + ReLU ----------
__global__ __launch_bounds__(256) void ln2conv1_k(const float* __restrict__ vl,
                                                  const float* __restrict__ g,
                                                  const float* __restrict__ bt,
                                                  const float* __restrict__ w1,
                                                  const float* __restrict__ g1,
                                                  const float* __restrict__ b1,
                                                  const float* __restrict__ m1,
                                                  const float* __restrict__ v1,
                                                  float* __restrict__ h1) {
    __shared__ float row[4][96];
    int wv = threadIdx.x >> 6, lane = threadIdx.x & 63;
    int pix = blockIdx.x * 4 + wv;
    const float* vr = vl + (size_t)pix * DIMC;
    float a0 = vr[lane];
    float a1 = (lane < 32) ? vr[64 + lane] : 0.f;
    float s = a0 + a1, q = a0 * a0 + a1 * a1;
    for (int o = 32; o; o >>= 1) { s += __shfl_xor(s, o, 64); q += __shfl_xor(q, o, 64); }
    float m = s * (1.f / 96.f);
    float inv = rsqrtf(q * (1.f / 96.f) - m * m + EPSF);
    row[wv][lane] = (a0 - m) * inv * g[lane] + bt[lane];
    if (lane < 32) row[wv][64 + lane] = (a1 - m) * inv * g[64 + lane] + bt[64 + lane];
    __syncthreads();
    if (lane < 24) {
        const float* wr = w1 + lane * 96;
        float acc = 0.f;
#pragma unroll 8
        for (int c = 0; c < 96; ++c) acc = fmaf(row[wv][c], wr[c], acc);
        float bn = (acc - m1[lane]) * rsqrtf(v1[lane] + EPSF) * g1[lane] + b1[lane];
        int b = pix / LL, pos = pix % LL;
        h1[((size_t)b * 24 + lane) * LL + pos] = fmaxf(bn, 0.f);
    }
}

// ---------- 7. conv3x3 (24->24) + BN + ReLU ----------
__global__ __launch_bounds__(256) void conv2_k(const float* __restrict__ h1,
                                               const float* __restrict__ w2,
                                               const float* __restrict__ g2,
                                               const float* __restrict__ b2,
                                               const float* __restrict__ m2,
                                               const float* __restrict__ v2,
                                               float* __restrict__ h2) {
    int i = blockIdx.x * 256 + threadIdx.x;
    int pos = i % LL, mo = (i / LL) % 24, b = i / (LL * 24);
    int hh = pos / WWD, ww = pos % WWD;
    float acc = 0.f;
    for (int c = 0; c < 24; ++c) {
        const float* src = h1 + ((size_t)b * 24 + c) * LL;
        const float* wk = w2 + ((size_t)(mo * 24 + c)) * 9;
#pragma unroll
        for (int ky = 0; ky < 3; ++ky) {
            int y = hh + ky - 1;
            if ((unsigned)y >= HH) continue;
#pragma unroll
            for (int kx = 0; kx < 3; ++kx) {
                int xq = ww + kx - 1;
                if ((unsigned)xq >= WWD) continue;
                acc = fmaf(wk[ky * 3 + kx], src[y * WWD + xq], acc);
            }
        }
    }
    float bn = (acc - m2[mo]) * rsqrtf(v2[mo] + EPSF) * g2[mo] + b2[mo];
    h2[i] = fmaxf(bn, 0.f);
}

// ---------- 8. conv1x1 (24->96) + BN ----------
__global__ __launch_bounds__(256) void conv3_k(const float* __restrict__ h2,
                                               const float* __restrict__ w3,
                                               const float* __restrict__ g3,
                                               const float* __restrict__ b3,
                                               const float* __restrict__ m3,
                                               const float* __restrict__ v3,
                                               float* __restrict__ h3) {
    int i = blockIdx.x * 256 + threadIdx.x;
    int pos = i % LL, c = (i / LL) % DIMC, b = i / (LL * DIMC);
    const float* wr = w3 + c * 24;
    float acc = 0.f;
#pragma unroll
    for (int mo = 0; mo < 24; ++mo)
        acc = fmaf(wr[mo], h2[((size_t)b * 24 + mo) * LL + pos], acc);
    h3[i] = (acc - m3[c]) * rsqrtf(v3[c] + EPSF) * g3[c] + b3[c];
}

// ---------- 9. SE pool ----------
__global__ __launch_bounds__(256) void pool_k(const float* __restrict__ h3,
                                              float* __restrict__ pooled) {
    int bc = blockIdx.x;
    const float* p = h3 + (size_t)bc * LL;
    float s = 0.f;
    for (int i = threadIdx.x; i < LL; i += 256) s += p[i];
    for (int o = 32; o; o >>= 1) s += __shfl_xor(s, o, 64);
    __shared__ float wsum[4];
    if ((threadIdx.x & 63) == 0) wsum[threadIdx.x >> 6] = s;
    __syncthreads();
    if (threadIdx.x == 0) pooled[bc] = (wsum[0] + wsum[1] + wsum[2] + wsum[3]) * (1.f / 3136.f);
}

// ---------- 10. SE MLP ----------
__global__ __launch_bounds__(128) void semlp_k(const float* __restrict__ pooled,
                                               const float* __restrict__ sw1,
                                               const float* __restrict__ sw2,
                                               float* __restrict__ sew) {
    __shared__ float pl[2][96];
    __shared__ float hid[2][24];
    for (int i = threadIdx.x; i < 192; i += 128) pl[i / 96][i % 96] = pooled[i];
    __syncthreads();
    if (threadIdx.x < 48) {
        int b = threadIdx.x / 24, mo = threadIdx.x % 24;
        float acc = 0.f;
        for (int c = 0; c < 96; ++c) acc = fmaf(pl[b][c], sw1[mo * 96 + c], acc);
        hid[b][mo] = fmaxf(acc, 0.f);
    }
    __syncthreads();
    for (int i = threadIdx.x; i < 192; i += 128) {
        int b = i / 96, c = i % 96;
        float acc = 0.f;
        for (int mo = 0; mo < 24; ++mo) acc = fmaf(hid[b][mo], sw2[c * 24 + mo], acc);
        sew[i] = 1.f / (1.f + __expf(-acc));
    }
}

// ---------- 11. final ----------
__global__ __launch_bounds__(256) void final_k(const float* __restrict__ h3,
                                               const float* __restrict__ sew,
                                               const float* __restrict__ vl,
                                               const float* __restrict__ sc2,
                                               float* __restrict__ out) {
    int i = blockIdx.x * 256 + threadIdx.x;
    int pos = i % LL, c = (i / LL) % DIMC, b = i / (LL * DIMC);
    out[i] = fmaf(h3[i], sew[b * DIMC + c],
                  sc2[c] * vl[((size_t)b * LL + pos) * DIMC + c]);
}

extern "C" void kernel_launch(void* const* d_in, const int* in_sizes, int n_in,
                              void* d_out, int out_size, void* d_ws, size_t ws_size,
                              hipStream_t stream) {
    const float* x    = (const float*)d_in[0];
    const float* n1g  = (const float*)d_in[1];
    const float* n1b  = (const float*)d_in[2];
    const float* ipw  = (const float*)d_in[3];
    const float* cw   = (const float*)d_in[4];
    const float* cb   = (const float*)d_in[5];
    const float* xpw  = (const float*)d_in[6];
    const float* dtw  = (const float*)d_in[7];
    const float* dtb  = (const float*)d_in[8];
    const float* alog = (const float*)d_in[9];
    const float* dsv  = (const float*)d_in[10];
    const float* ong  = (const float*)d_in[11];
    const float* onb  = (const float*)d_in[12];
    const float* opw  = (const float*)d_in[13];
    const float* sc1  = (const float*)d_in[14];
    const float* n2g  = (const float*)d_in[15];
    const float* n2b  = (const float*)d_in[16];
    const float* w1   = (const float*)d_in[17];
    const float* g1   = (const float*)d_in[18];
    const float* b1   = (const float*)d_in[19];
    const float* m1   = (const float*)d_in[20];
    const float* v1   = (const float*)d_in[21];
    const float* w2   = (const float*)d_in[22];
    const float* g2   = (const float*)d_in[23];
    const float* b2   = (const float*)d_in[24];
    const float* m2   = (const float*)d_in[25];
    const float* v2   = (const float*)d_in[26];
    const float* w3   = (const float*)d_in[27];
    const float* g3   = (const float*)d_in[28];
    const float* b3   = (const float*)d_in[29];
    const float* m3   = (const float*)d_in[30];
    const float* v3   = (const float*)d_in[31];
    const float* sw1  = (const float*)d_in[32];
    const float* sw2  = (const float*)d_in[33];
    const float* sc2  = (const float*)d_in[34];
    float* ws = (float*)d_ws;
    float* out = (float*)d_out;

    gemm1_k<<<dim3(NPIX / 32, 4), 256, 0, stream>>>(x, n1g, n1b, ipw,
                                                    ws + OFF_XCRAW, ws + OFF_ZS);
    dwconv_k<<<BB * DINC, 448, 0, stream>>>(ws + OFF_XCRAW, cw, cb, ws + OFF_XCONV);
    gemmx_k<<<dim3(NPIX / 32, 4), 256, 0, stream>>>(ws + OFF_XCONV, xpw, ws + OFF_DTS,
                                                    ws + OFF_BCB, ws + OFF_BCC, ws + OFF_XSCANT);

    pass1_k<<<BB * KDIR * 3 * NCH, 64, 0, stream>>>(
        ws + OFF_DTS, ws + OFF_BCB, ws + OFF_BCC, alog, dtw, dtb,
        ws + OFF_XSCANT, ws + OFF_HENDT, ws + OFF_SUMDT, ws + OFF_YS, ws + OFF_CUMD);
    scan2_k<<<(NCHAIN * NSTC) / 256, 256, 0, stream>>>(ws + OFF_HENDT, ws + OFF_SUMDT, alog);
    pass2_k<<<BB * KDIR * NCH, 256, 0, stream>>>(
        ws + OFF_BCC, alog, ws + OFF_HENDT, ws + OFF_CUMD, ws + OFF_YS);

    gemm2_k<<<NPIX / 16, 256, 0, stream>>>(ws + OFF_YS, ws + OFF_XSCANT, dsv,
                                           ong, onb, ws + OFF_ZS, opw, x, sc1, ws + OFF_VL);
    ln2conv1_k<<<NPIX / 4, 256, 0, stream>>>(ws + OFF_VL, n2g, n2b, w1, g1, b1, m1, v1,
                                             ws + OFF_H1);
    conv2_k<<<(BB * 24 * LL) / 256, 256, 0, stream>>>(ws + OFF_H1, w2, g2, b2, m2, v2,
                                                      ws + OFF_H2);
    conv3_k<<<(BB * DIMC * LL) / 256, 256, 0, stream>>>(ws + OFF_H2, w3, g3, b3, m3, v3,
                                                        ws + OFF_H3);
    pool_k<<<BB * DIMC, 256, 0, stream>>>(ws + OFF_H3, ws + OFF_POOL);
    semlp_k<<<1, 128, 0, stream>>>(ws + OFF_POOL, sw1, sw2, ws + OFF_SEW);
    final_k<<<(BB * DIMC * LL) / 256, 256, 0, stream>>>(ws + OFF_H3, ws + OFF_SEW, ws + OFF_VL,
                                                        sc2, out);
    (void)in_sizes; (void)n_in; (void)out_size; (void)ws_size;
}

// Round 16
// 218.797 us; speedup vs baseline: 1.1037x; 1.0501x over previous
//
#include <hip/hip_runtime.h>
#include <math.h>

#define DIMC 96
#define DINC 192
#define NSTC 16
#define DTRC 6
#define KDIR 4
#define BB   2
#define HH   56
#define WWD  56
#define LL   3136
#define NPIX (BB*LL)           // 6272
#define EPSF 1e-5f
#define NCH  98                // chunks per chain
#define LC   32                // chunk length (98*32=3136)
#define NCHAIN (BB*KDIR*DINC)  // 1536
#define NCOLS 152              // 4*38

// ---------- workspace layout (float offsets) ----------
#define OFF_XCRAW  0u          // 1204224 (gemm1->dwconv)
#define OFF_XCONV  1204224u    // 1204224 (dwconv->gemmx)
#define OFF_ZS     2408448u    // 1204224 (gemm1->gemm2)
#define OFF_DTS    3612672u    // 150528
#define OFF_BCB    3763200u    // 401408
#define OFF_BCC    4164608u    // 401408
#define OFF_XSCANT 4566016u    // 2408448 [b*2+slice][l][d] (2 slices; k>=2 read reversed)
#define OFF_CUMD   6974464u    // 4816896 (pass1->pass2)
#define OFF_YS     11791360u   // 4816896 (pass1->pass2 in-place ->gemm2)
#define OFF_HENDT  0u          // 2408448 = 8*98*16*192, reuses XCRAW+XCONV (dead after gemmx)
#define OFF_SUMDT  16608256u   // 150528 -> ends 16758784
// post-pass2 (CUMD dead):
#define OFF_VL     6974464u    // 602112
#define OFF_H1     7576576u    // 150528
#define OFF_H2     7727104u    // 150528
#define OFF_H3     7877632u    // 602112
#define OFF_POOL   8479744u    // 192
#define OFF_SEW    8479936u    // 192

__device__ __forceinline__ float siluf(float x) { return x / (1.f + __expf(-x)); }
__device__ __forceinline__ float softplusf(float x) {
    return fmaxf(x, 0.f) + __logf(1.f + __expf(-fabsf(x)));
}
__device__ __forceinline__ float fexp2(float x) {
#if __has_builtin(__builtin_amdgcn_exp2f)
    return __builtin_amdgcn_exp2f(x);
#else
    return exp2f(x);
#endif
}
#define LOG2E 1.44269504088896f

// ---------- 1. fused LN1 + in_proj GEMM. grid (98,4) x 256. M=64,N=96 ----------
__global__ __launch_bounds__(256) void gemm1_k(const float* __restrict__ x,
                                               const float* __restrict__ g,
                                               const float* __restrict__ bt,
                                               const float* __restrict__ W,
                                               float* __restrict__ xcr,
                                               float* __restrict__ zs) {
    __shared__ float xT[64 * 97];
    __shared__ float wT[96 * 100];
    __shared__ float mA[64], iA[64];
    int row0 = blockIdx.x * 64;
    int b = row0 / LL, pos0 = row0 % LL;
    int c0 = blockIdx.y * 96;
    for (int f = threadIdx.x; f < 96 * 16; f += 256) {
        int ch = f >> 4, po = (f & 15) * 4;
        float4 v = *(const float4*)&x[((size_t)b * DIMC + ch) * LL + pos0 + po];
        xT[(po + 0) * 97 + ch] = v.x; xT[(po + 1) * 97 + ch] = v.y;
        xT[(po + 2) * 97 + ch] = v.z; xT[(po + 3) * 97 + ch] = v.w;
    }
    for (int f = threadIdx.x; f < 96 * 24; f += 256) {
        int r = f / 24, kq = (f % 24) * 4;
        *(float4*)&wT[r * 100 + kq] = *(const float4*)&W[(size_t)(c0 + r) * DIMC + kq];
    }
    __syncthreads();
    if (threadIdx.x < 64) {
        float s = 0.f, q = 0.f;
        const float* xr = &xT[threadIdx.x * 97];
        for (int c = 0; c < 96; ++c) { float v = xr[c]; s += v; q = fmaf(v, v, q); }
        float m = s * (1.f / 96.f);
        mA[threadIdx.x] = m;
        iA[threadIdx.x] = rsqrtf(q * (1.f / 96.f) - m * m + EPSF);
    }
    __syncthreads();
    for (int e = threadIdx.x; e < 64 * 96; e += 256) {
        int row = e / 96, col = e - row * 96;
        float v = xT[row * 97 + col];
        xT[row * 97 + col] = (v - mA[row]) * iA[row] * g[col] + bt[col];
    }
    __syncthreads();
    int tc = threadIdx.x & 15, tr = threadIdx.x >> 4;
    float acc[4][6] = {};
    for (int k = 0; k < 96; ++k) {
        float xv[4], wv[6];
#pragma unroll
        for (int i = 0; i < 4; ++i) xv[i] = xT[(4 * tr + i) * 97 + k];
#pragma unroll
        for (int j = 0; j < 6; ++j) wv[j] = wT[(tc + 16 * j) * 100 + k];
#pragma unroll
        for (int i = 0; i < 4; ++i)
#pragma unroll
            for (int j = 0; j < 6; ++j) acc[i][j] = fmaf(xv[i], wv[j], acc[i][j]);
    }
    int pos = pos0 + 4 * tr;
    if (c0 < DINC) {
#pragma unroll
        for (int j = 0; j < 6; ++j) {
            int col = c0 + tc + 16 * j;
            float4 v = make_float4(acc[0][j], acc[1][j], acc[2][j], acc[3][j]);
            *(float4*)&xcr[((size_t)b * DINC + col) * LL + pos] = v;
        }
    } else {
#pragma unroll
        for (int i = 0; i < 4; ++i)
#pragma unroll
            for (int j = 0; j < 6; ++j) {
                int zc = c0 - DINC + tc + 16 * j;
                zs[(size_t)(row0 + 4 * tr + i) * DINC + zc] = siluf(acc[i][j]);
            }
    }
}

// ---------- 2. depthwise 3x3 conv + silu -> xconv ----------
__global__ __launch_bounds__(448) void dwconv_k(const float* __restrict__ xcr,
                                                const float* __restrict__ cw,
                                                const float* __restrict__ cb,
                                                float* __restrict__ xconv) {
    __shared__ float P[56 * 57];
    int bd = blockIdx.x;
    int d = bd % DINC;
    size_t base = (size_t)bd * LL;
    for (int t = threadIdx.x; t < LL; t += 448)
        P[(t / 56) * 57 + (t % 56)] = xcr[base + t];
    float wk[9];
#pragma unroll
    for (int q = 0; q < 9; ++q) wk[q] = cw[d * 9 + q];
    float bias = cb[d];
    __syncthreads();
    for (int t = threadIdx.x; t < LL; t += 448) {
        int h = t / 56, w = t % 56;
        float acc = bias;
#pragma unroll
        for (int ky = 0; ky < 3; ++ky) {
            int y = h + ky - 1;
            if ((unsigned)y >= 56u) continue;
#pragma unroll
            for (int kx = 0; kx < 3; ++kx) {
                int xq = w + kx - 1;
                if ((unsigned)xq >= 56u) continue;
                acc = fmaf(wk[ky * 3 + kx], P[y * 57 + xq], acc);
            }
        }
        xconv[base + t] = siluf(acc);
    }
}

// ---------- 3. x_proj GEMM, band = direction. grid (196,4) x 256. M=32,N=38 ----------
__global__ __launch_bounds__(256) void gemmx_k(const float* __restrict__ xconv,
                                               const float* __restrict__ xpw,
                                               float* __restrict__ dts,
                                               float* __restrict__ bcB,
                                               float* __restrict__ bcC,
                                               float* __restrict__ xscanT) {
    __shared__ float xT[32 * 49];
    __shared__ float wT[38 * 52];
    int row0 = blockIdx.x * 32;
    int b = row0 / LL, pos0 = row0 % LL;
    int by = blockIdx.y;               // direction k
    int m = threadIdx.x & 31, cg = threadIdx.x >> 5;
    float acc[5] = {};
    for (int kc = 0; kc < 4; ++kc) {
        if (kc) __syncthreads();
        for (int f = threadIdx.x; f < 48 * 8; f += 256) {
            int dd = f >> 3, po = (f & 7) * 4;
            float4 v = *(const float4*)&xconv[((size_t)b * DINC + kc * 48 + dd) * LL + pos0 + po];
            xT[(po + 0) * 49 + dd] = v.x; xT[(po + 1) * 49 + dd] = v.y;
            xT[(po + 2) * 49 + dd] = v.z; xT[(po + 3) * 49 + dd] = v.w;
        }
        for (int f = threadIdx.x; f < 38 * 12; f += 256) {
            int r = f / 12, kq = (f % 12) * 4;
            *(float4*)&wT[r * 52 + kq] =
                *(const float4*)&xpw[(size_t)(by * 38 + r) * DINC + kc * 48 + kq];
        }
        __syncthreads();
#pragma unroll 4
        for (int k = 0; k < 48; ++k) {
            float xv = xT[m * 49 + k];
#pragma unroll
            for (int j = 0; j < 5; ++j) {
                int idx = cg + 8 * j;
                float wv = (idx < 38) ? wT[idx * 52 + k] : 0.f;
                acc[j] = fmaf(xv, wv, acc[j]);
            }
        }
        if (by == 0) {
            for (int f = threadIdx.x; f < 32 * 48; f += 256) {
                int i = f / 48, dd = f - 48 * (f / 48);
                float v = xT[i * 49 + dd];
                int pos = pos0 + i;
                int hh = pos / 56, w = pos - 56 * hh;
                int lt = w * 56 + hh;
                size_t bb = (size_t)b * 2;
                int col = kc * 48 + dd;
                xscanT[(bb * LL + pos) * DINC + col] = v;
                xscanT[((bb + 1) * LL + lt) * DINC + col] = v;
            }
        }
    }
    {
        int pos = pos0 + m;
        int h = pos / 56, w = pos - 56 * h;
        int lt = w * 56 + h;
        int l = (by == 0) ? pos : (by == 1) ? lt : (by == 2) ? (LL - 1 - pos) : (LL - 1 - lt);
        size_t rb = (size_t)(b * KDIR + by) * LL + l;
#pragma unroll
        for (int j = 0; j < 5; ++j) {
            int idx = cg + 8 * j;
            if (idx >= 38) continue;
            float v = acc[j];
            if (idx < DTRC)    dts[rb * DTRC + idx] = v;
            else if (idx < 22) bcB[rb * NSTC + (idx - 6)] = v;
            else               bcC[rb * NSTC + (idx - 22)] = v;
        }
    }
}

// ---------- 4a. pass1: d-per-thread local scan. grid 8*3*98 = 2352 x 64 ----------
__global__ __launch_bounds__(64) void pass1_k(const float* __restrict__ dts,
                                              const float* __restrict__ bcB,
                                              const float* __restrict__ bcC,
                                              const float* __restrict__ alog,
                                              const float* __restrict__ dtw,
                                              const float* __restrict__ dtb,
                                              const float* __restrict__ xscanT,
                                              float* __restrict__ hendT,
                                              float* __restrict__ sumdT,
                                              float* __restrict__ ysT,
                                              float* __restrict__ cumdT) {
    __shared__ float sdt[LC * 7];
    __shared__ float sB[LC * 16];
    __shared__ float sC[LC * 16];
    int blk = blockIdx.x;
    int c = blk % NCH;
    int dtile = (blk / NCH) % 3;
    int bk = blk / (NCH * 3);
    int k = bk & 3, b = bk >> 2;
    int l0 = c * LC;
    int t = threadIdx.x;
    int d = dtile * 64 + t;
    const float* dsrc = dts + ((size_t)bk * LL + l0) * DTRC;
    for (int f = t; f < LC * DTRC; f += 64) sdt[(f / DTRC) * 7 + (f % DTRC)] = dsrc[f];
    const float* bB = bcB + ((size_t)bk * LL + l0) * NSTC;
    const float* bC = bcC + ((size_t)bk * LL + l0) * NSTC;
    for (int f = t; f < LC * NSTC; f += 64) { sB[f] = bB[f]; sC[f] = bC[f]; }
    float wr[DTRC];
    {
        const float* wp = dtw + ((size_t)k * DINC + d) * DTRC;
#pragma unroll
        for (int r = 0; r < DTRC; ++r) wr[r] = wp[r];
    }
    float bias = dtb[k * DINC + d];
    float An2[NSTC];
    {
        const float* ap = alog + ((size_t)(k * DINC + d)) * NSTC;
#pragma unroll
        for (int n = 0; n < NSTC; ++n) An2[n] = -__expf(ap[n]) * LOG2E;
    }
    __syncthreads();
    float h[NSTC];
#pragma unroll
    for (int n = 0; n < NSTC; ++n) h[n] = 0.f;
    float cum = 0.f;
    bool rev = (k >= 2);
    const float* xbase = xscanT + ((size_t)(b * 2 + (k & 1)) * LL) * DINC + d;
    int xi0 = rev ? (LL - 1 - l0) : l0;
    float* yrow = ysT + ((size_t)bk * LL + l0) * DINC + d;
    float* crow = cumdT + ((size_t)bk * LL + l0) * DINC + d;
#pragma unroll 8
    for (int s = 0; s < LC; ++s) {
        float acc = bias;
#pragma unroll
        for (int r = 0; r < DTRC; ++r) acc = fmaf(wr[r], sdt[s * 7 + r], acc);
        float dv = softplusf(acc);
        float xv = xbase[(size_t)(rev ? (xi0 - s) : (xi0 + s)) * DINC];
        cum += dv;
        float dx = dv * xv;
        const float4* B4 = (const float4*)&sB[s * 16];
        const float4* C4 = (const float4*)&sC[s * 16];
        float y = 0.f;
#pragma unroll
        for (int nq = 0; nq < 4; ++nq) {
            float4 Bv = B4[nq], Cv = C4[nq];
            float e0 = fexp2(An2[nq * 4 + 0] * dv);
            h[nq * 4 + 0] = fmaf(e0, h[nq * 4 + 0], dx * Bv.x);
            y = fmaf(h[nq * 4 + 0], Cv.x, y);
            float e1 = fexp2(An2[nq * 4 + 1] * dv);
            h[nq * 4 + 1] = fmaf(e1, h[nq * 4 + 1], dx * Bv.y);
            y = fmaf(h[nq * 4 + 1], Cv.y, y);
            float e2 = fexp2(An2[nq * 4 + 2] * dv);
            h[nq * 4 + 2] = fmaf(e2, h[nq * 4 + 2], dx * Bv.z);
            y = fmaf(h[nq * 4 + 2], Cv.z, y);
            float e3 = fexp2(An2[nq * 4 + 3] * dv);
            h[nq * 4 + 3] = fmaf(e3, h[nq * 4 + 3], dx * Bv.w);
            y = fmaf(h[nq * 4 + 3], Cv.w, y);
        }
        yrow[(size_t)s * DINC] = y;
        crow[(size_t)s * DINC] = cum;
    }
#pragma unroll
    for (int n = 0; n < NSTC; ++n)
        hendT[((size_t)(bk * NCH + c) * NSTC + n) * DINC + d] = h[n];
    sumdT[(size_t)(bk * NCH + c) * DINC + d] = cum;
}

// ---------- 4b. scan2: thread=(d,n), serial over chunks. grid 96 x 256 ----------
__global__ __launch_bounds__(256) void scan2_k(float* __restrict__ hendT,
                                               const float* __restrict__ sumdT,
                                               const float* __restrict__ alog) {
    int gid = blockIdx.x * 256 + threadIdx.x;
    int d = gid % DINC;
    int n = (gid / DINC) % NSTC;
    int bk = gid / (DINC * NSTC);
    int k = bk & 3;
    float An2 = -__expf(alog[((size_t)(k * DINC + d)) * NSTC + n]) * LOG2E;
    float h = 0.f;
#pragma unroll 4
    for (int c = 0; c < NCH; ++c) {
        size_t idx = ((size_t)(bk * NCH + c) * NSTC + n) * DINC + d;
        float he = hendT[idx];
        float sd = sumdT[(size_t)(bk * NCH + c) * DINC + d];
        hendT[idx] = h;
        h = fmaf(fexp2(An2 * sd), h, he);
    }
}

// ---------- 4c. pass2: y += sum_n C*exp2(A2*cumd)*hpre. grid 784 x 256 ----------
__global__ __launch_bounds__(256) void pass2_k(const float* __restrict__ bcC,
                                               const float* __restrict__ alog,
                                               const float* __restrict__ hpreT,
                                               const float* __restrict__ cumdT,
                                               float* __restrict__ ysT) {
    __shared__ float sA2[DINC * 17];
    __shared__ float sH[DINC * 17];
    __shared__ float sC[LC * NSTC];
    int blk = blockIdx.x;
    int c = blk % NCH;
    int bk = blk / NCH;
    int k = bk & 3;
    int l0 = c * LC;
    int tid = threadIdx.x;
    const float* ap = alog + (size_t)k * DINC * NSTC;
    for (int f = tid; f < DINC * NSTC; f += 256) {
        int dq = f / NSTC, n = f % NSTC;
        sA2[dq * 17 + n] = -__expf(ap[f]) * LOG2E;
    }
    for (int f = tid; f < DINC * NSTC; f += 256) {
        int n = f / DINC, dq = f % DINC;
        sH[dq * 17 + n] = hpreT[((size_t)(bk * NCH + c) * NSTC + n) * DINC + dq];
    }
    const float* bC = bcC + ((size_t)bk * LL + l0) * NSTC;
    for (int f = tid; f < LC * NSTC; f += 256) sC[f] = bC[f];
    __syncthreads();
    for (int e = tid; e < LC * DINC; e += 256) {
        int li = e / DINC, d = e - DINC * (e / DINC);
        size_t gq = ((size_t)bk * LL + l0 + li) * DINC + d;
        float cd = cumdT[gq];
        float y = ysT[gq];
        const float* A = &sA2[d * 17];
        const float* Hp = &sH[d * 17];
        const float* Cp = &sC[li * NSTC];
#pragma unroll
        for (int n = 0; n < NSTC; ++n)
            y = fmaf(Hp[n] * fexp2(A[n] * cd), Cp[n], y);
        ysT[gq] = y;
    }
}

// ---------- 5. fused combine + out_norm*silu(z) + out_proj + residual. M=16, grid 392 ----------
__global__ __launch_bounds__(256) void gemm2_k(const float* __restrict__ ysT,
                                               const float* __restrict__ xscanT,
                                               const float* __restrict__ dsv,
                                               const float* __restrict__ g,
                                               const float* __restrict__ bt,
                                               const float* __restrict__ zs,
                                               const float* __restrict__ opw,
                                               const float* __restrict__ x,
                                               const float* __restrict__ sc1,
                                               float* __restrict__ vl) {
    __shared__ float xT[16 * 193];
    __shared__ float wT[96 * 52];
    __shared__ float mA[16], iA[16];
    __shared__ float sD[DINC];
    int row0 = blockIdx.x * 16;
    int b = row0 / LL, pos0 = row0 % LL;
    if (threadIdx.x < DINC)
        sD[threadIdx.x] = dsv[threadIdx.x] + dsv[DINC + threadIdx.x] +
                          dsv[2 * DINC + threadIdx.x] + dsv[3 * DINC + threadIdx.x];
    __syncthreads();
    size_t base = (size_t)b * KDIR * LL;
    size_t xbase = (size_t)b * 2 * LL;
    for (int f = threadIdx.x; f < 16 * DINC; f += 256) {
        int r = f / DINC, d = f - DINC * (f / DINC);
        int pos = pos0 + r;
        int hh = pos / 56, w = pos - 56 * hh;
        int lt = w * 56 + hh;
        float y = ysT[(base + pos) * DINC + d]
                + ysT[(base + LL + lt) * DINC + d]
                + ysT[(base + 2 * LL + (LL - 1 - pos)) * DINC + d]
                + ysT[(base + 3 * LL + (LL - 1 - lt)) * DINC + d];
        float xv = xscanT[(xbase + pos) * DINC + d];
        xT[r * 193 + d] = fmaf(xv, sD[d], y);
    }
    __syncthreads();
    {
        int r = threadIdx.x >> 4, sc = threadIdx.x & 15;
        float s = 0.f, q = 0.f;
#pragma unroll
        for (int j = 0; j < 12; ++j) {
            float v = xT[r * 193 + sc + 16 * j];
            s += v; q = fmaf(v, v, q);
        }
        s += __shfl_xor(s, 1, 16); q += __shfl_xor(q, 1, 16);
        s += __shfl_xor(s, 2, 16); q += __shfl_xor(q, 2, 16);
        s += __shfl_xor(s, 4, 16); q += __shfl_xor(q, 4, 16);
        s += __shfl_xor(s, 8, 16); q += __shfl_xor(q, 8, 16);
        if (sc == 0) {
            float m = s * (1.f / 192.f);
            mA[r] = m;
            iA[r] = rsqrtf(q * (1.f / 192.f) - m * m + EPSF);
        }
    }
    __syncthreads();
    for (int e = threadIdx.x; e < 16 * 192; e += 256) {
        int row = e / 192, col = e - row * 192;
        float v = xT[row * 193 + col];
        float z = zs[(size_t)row0 * DINC + e];
        xT[row * 193 + col] = ((v - mA[row]) * iA[row] * g[col] + bt[col]) * z;
    }
    int tc = threadIdx.x & 15, tr = threadIdx.x >> 4;
    float acc[6] = {};
    for (int kc = 0; kc < 4; ++kc) {
        __syncthreads();
        for (int f = threadIdx.x; f < 96 * 12; f += 256) {
            int r = f / 12, kq = (f % 12) * 4;
            *(float4*)&wT[r * 52 + kq] = *(const float4*)&opw[(size_t)r * DINC + kc * 48 + kq];
        }
        __syncthreads();
#pragma unroll 4
        for (int k = 0; k < 48; ++k) {
            float xv = xT[tr * 193 + kc * 48 + k];
#pragma unroll
            for (int j = 0; j < 6; ++j) acc[j] = fmaf(xv, wT[(tc + 16 * j) * 52 + k], acc[j]);
        }
    }
    {
        int pos = pos0 + tr;
#pragma unroll
        for (int j = 0; j < 6; ++j) {
            int col = tc + 16 * j;
            float v = fmaf(sc1[col], x[((size_t)b * DIMC + col) * LL + pos], acc[j]);
            vl[(size_t)(row0 + tr) * DIMC + col] = v;
        }
    }
}

// ---------- 6. LN2 + conv1x1(96->24) + BN + ReLU ----------
__global__ __launch_bounds__(256) void ln2conv1_k(const float* __restrict__ vl,
                                                  const float* __restrict__ g,
                                                  const float* __restrict__ bt,
                                                  const float* __restrict__ w1,
                                                  const float* __restrict__ g1,
                                                  const float* __restrict__ b1,
                                                  const float* __restrict__ m1,
                                                  const float* __restrict__ v1,
                                                  float* __restrict__ h1) {
    __shared__ float row[4][96];
    int wv = threadIdx.x >> 6, lane = threadIdx.x & 63;
    int pix = blockIdx.x * 4 + wv;
    const float* vr = vl + (size_t)pix * DIMC;
    float a0 = vr[lane];
    float a1 = (lane < 32) ? vr[64 + lane] : 0.f;
    float s = a0 + a1, q = a0 * a0 + a1 * a1;
    for (int o = 32; o; o >>= 1) { s += __shfl_xor(s, o, 64); q += __shfl_xor(q, o, 64); }
    float m = s * (1.f / 96.f);
    float inv = rsqrtf(q * (1.f / 96.f) - m * m + EPSF);
    row[wv][lane] = (a0 - m) * inv * g[lane] + bt[lane];
    if (lane < 32) row[wv][64 + lane] = (a1 - m) * inv * g[64 + lane] + bt[64 + lane];
    __syncthreads();
    if (lane < 24) {
        const float* wr = w1 + lane * 96;
        float acc = 0.f;
#pragma unroll 8
        for (int c = 0; c < 96; ++c) acc = fmaf(row[wv][c], wr[c], acc);
        float bn = (acc - m1[lane]) * rsqrtf(v1[lane] + EPSF) * g1[lane] + b1[lane];
        int b = pix / LL, pos = pix % LL;
        h1[((size_t)b * 24 + lane) * LL + pos] = fmaxf(bn, 0.f);
    }
}

// ---------- 7. conv3x3 (24->24) + BN + ReLU ----------
__global__ __launch_bounds__(256) void conv2_k(const float* __restrict__ h1,
                                               const float* __restrict__ w2,
                                               const float* __restrict__ g2,
                                               const float* __restrict__ b2,
                                               const float* __restrict__ m2,
                                               const float* __restrict__ v2,
                                               float* __restrict__ h2) {
    int i = blockIdx.x * 256 + threadIdx.x;
    int pos = i % LL, mo = (i / LL) % 24, b = i / (LL * 24);
    int hh = pos / WWD, ww = pos % WWD;
    float acc = 0.f;
    for (int c = 0; c < 24; ++c) {
        const float* src = h1 + ((size_t)b * 24 + c) * LL;
        const float* wk = w2 + ((size_t)(mo * 24 + c)) * 9;
#pragma unroll
        for (int ky = 0; ky < 3; ++ky) {
            int y = hh + ky - 1;
            if ((unsigned)y >= HH) continue;
#pragma unroll
            for (int kx = 0; kx < 3; ++kx) {
                int xq = ww + kx - 1;
                if ((unsigned)xq >= WWD) continue;
                acc = fmaf(wk[ky * 3 + kx], src[y * WWD + xq], acc);
            }
        }
    }
    float bn = (acc - m2[mo]) * rsqrtf(v2[mo] + EPSF) * g2[mo] + b2[mo];
    h2[i] = fmaxf(bn, 0.f);
}

// ---------- 8. conv1x1 (24->96) + BN ----------
__global__ __launch_bounds__(256) void conv3_k(const float* __restrict__ h2,
                                               const float* __restrict__ w3,
                                               const float* __restrict__ g3,
                                               const float* __restrict__ b3,
                                               const float* __restrict__ m3,
                                               const float* __restrict__ v3,
                                               float* __restrict__ h3) {
    int i = blockIdx.x * 256 + threadIdx.x;
    int pos = i % LL, c = (i / LL) % DIMC, b = i / (LL * DIMC);
    const float* wr = w3 + c * 24;
    float acc = 0.f;
#pragma unroll
    for (int mo = 0; mo < 24; ++mo)
        acc = fmaf(wr[mo], h2[((size_t)b * 24 + mo) * LL + pos], acc);
    h3[i] = (acc - m3[c]) * rsqrtf(v3[c] + EPSF) * g3[c] + b3[c];
}

// ---------- 9. SE pool ----------
__global__ __launch_bounds__(256) void pool_k(const float* __restrict__ h3,
                                              float* __restrict__ pooled) {
    int bc = blockIdx.x;
    const float* p = h3 + (size_t)bc * LL;
    float s = 0.f;
    for (int i = threadIdx.x; i < LL; i += 256) s += p[i];
    for (int o = 32; o; o >>= 1) s += __shfl_xor(s, o, 64);
    __shared__ float wsum[4];
    if ((threadIdx.x & 63) == 0) wsum[threadIdx.x >> 6] = s;
    __syncthreads();
    if (threadIdx.x == 0) pooled[bc] = (wsum[0] + wsum[1] + wsum[2] + wsum[3]) * (1.f / 3136.f);
}

// ---------- 10. SE MLP ----------
__global__ __launch_bounds__(128) void semlp_k(const float* __restrict__ pooled,
                                               const float* __restrict__ sw1,
                                               const float* __restrict__ sw2,
                                               float* __restrict__ sew) {
    __shared__ float pl[2][96];
    __shared__ float hid[2][24];
    for (int i = threadIdx.x; i < 192; i += 128) pl[i / 96][i % 96] = pooled[i];
    __syncthreads();
    if (threadIdx.x < 48) {
        int b = threadIdx.x / 24, mo = threadIdx.x % 24;
        float acc = 0.f;
        for (int c = 0; c < 96; ++c) acc = fmaf(pl[b][c], sw1[mo * 96 + c], acc);
        hid[b][mo] = fmaxf(acc, 0.f);
    }
    __syncthreads();
    for (int i = threadIdx.x; i < 192; i += 128) {
        int b = i / 96, c = i % 96;
        float acc = 0.f;
        for (int mo = 0; mo < 24; ++mo) acc = fmaf(hid[b][mo], sw2[c * 24 + mo], acc);
        sew[i] = 1.f / (1.f + __expf(-acc));
    }
}

// ---------- 11. final ----------
__global__ __launch_bounds__(256) void final_k(const float* __restrict__ h3,
                                               const float* __restrict__ sew,
                                               const float* __restrict__ vl,
                                               const float* __restrict__ sc2,
                                               float* __restrict__ out) {
    int i = blockIdx.x * 256 + threadIdx.x;
    int pos = i % LL, c = (i / LL) % DIMC, b = i / (LL * DIMC);
    out[i] = fmaf(h3[i], sew[b * DIMC + c],
                  sc2[c] * vl[((size_t)b * LL + pos) * DIMC + c]);
}

extern "C" void kernel_launch(void* const* d_in, const int* in_sizes, int n_in,
                              void* d_out, int out_size, void* d_ws, size_t ws_size,
                              hipStream_t stream) {
    const float* x    = (const float*)d_in[0];
    const float* n1g  = (const float*)d_in[1];
    const float* n1b  = (const float*)d_in[2];
    const float* ipw  = (const float*)d_in[3];
    const float* cw   = (const float*)d_in[4];
    const float* cb   = (const float*)d_in[5];
    const float* xpw  = (const float*)d_in[6];
    const float* dtw  = (const float*)d_in[7];
    const float* dtb  = (const float*)d_in[8];
    const float* alog = (const float*)d_in[9];
    const float* dsv  = (const float*)d_in[10];
    const float* ong  = (const float*)d_in[11];
    const float* onb  = (const float*)d_in[12];
    const float* opw  = (const float*)d_in[13];
    const float* sc1  = (const float*)d_in[14];
    const float* n2g  = (const float*)d_in[15];
    const float* n2b  = (const float*)d_in[16];
    const float* w1   = (const float*)d_in[17];
    const float* g1   = (const float*)d_in[18];
    const float* b1   = (const float*)d_in[19];
    const float* m1   = (const float*)d_in[20];
    const float* v1   = (const float*)d_in[21];
    const float* w2   = (const float*)d_in[22];
    const float* g2   = (const float*)d_in[23];
    const float* b2   = (const float*)d_in[24];
    const float* m2   = (const float*)d_in[25];
    const float* v2   = (const float*)d_in[26];
    const float* w3   = (const float*)d_in[27];
    const float* g3   = (const float*)d_in[28];
    const float* b3   = (const float*)d_in[29];
    const float* m3   = (const float*)d_in[30];
    const float* v3   = (const float*)d_in[31];
    const float* sw1  = (const float*)d_in[32];
    const float* sw2  = (const float*)d_in[33];
    const float* sc2  = (const float*)d_in[34];
    float* ws = (float*)d_ws;
    float* out = (float*)d_out;

    gemm1_k<<<dim3(NPIX / 64, 4), 256, 0, stream>>>(x, n1g, n1b, ipw,
                                                    ws + OFF_XCRAW, ws + OFF_ZS);
    dwconv_k<<<BB * DINC, 448, 0, stream>>>(ws + OFF_XCRAW, cw, cb, ws + OFF_XCONV);
    gemmx_k<<<dim3(NPIX / 32, 4), 256, 0, stream>>>(ws + OFF_XCONV, xpw, ws + OFF_DTS,
                                                    ws + OFF_BCB, ws + OFF_BCC, ws + OFF_XSCANT);

    pass1_k<<<BB * KDIR * 3 * NCH, 64, 0, stream>>>(
        ws + OFF_DTS, ws + OFF_BCB, ws + OFF_BCC, alog, dtw, dtb,
        ws + OFF_XSCANT, ws + OFF_HENDT, ws + OFF_SUMDT, ws + OFF_YS, ws + OFF_CUMD);
    scan2_k<<<(NCHAIN * NSTC) / 256, 256, 0, stream>>>(ws + OFF_HENDT, ws + OFF_SUMDT, alog);
    pass2_k<<<BB * KDIR * NCH, 256, 0, stream>>>(
        ws + OFF_BCC, alog, ws + OFF_HENDT, ws + OFF_CUMD, ws + OFF_YS);

    gemm2_k<<<NPIX / 16, 256, 0, stream>>>(ws + OFF_YS, ws + OFF_XSCANT, dsv,
                                           ong, onb, ws + OFF_ZS, opw, x, sc1, ws + OFF_VL);
    ln2conv1_k<<<NPIX / 4, 256, 0, stream>>>(ws + OFF_VL, n2g, n2b, w1, g1, b1, m1, v1,
                                             ws + OFF_H1);
    conv2_k<<<(BB * 24 * LL) / 256, 256, 0, stream>>>(ws + OFF_H1, w2, g2, b2, m2, v2,
                                                      ws + OFF_H2);
    conv3_k<<<(BB * DIMC * LL) / 256, 256, 0, stream>>>(ws + OFF_H2, w3, g3, b3, m3, v3,
                                                        ws + OFF_H3);
    pool_k<<<BB * DIMC, 256, 0, stream>>>(ws + OFF_H3, ws + OFF_POOL);
    semlp_k<<<1, 128, 0, stream>>>(ws + OFF_POOL, sw1, sw2, ws + OFF_SEW);
    final_k<<<(BB * DIMC * LL) / 256, 256, 0, stream>>>(ws + OFF_H3, ws + OFF_SEW, ws + OFF_VL,
                                                        sc2, out);
    (void)in_sizes; (void)n_in; (void)out_size; (void)ws_size;
}